// Round 2
// baseline (293.345 us; speedup 1.0000x reference)
//
#include <hip/hip_runtime.h>
#include <math.h>

#define SPAT 1600
#define BSZ 8
#define DM 256
#define NH 8
#define DH 32

// ---------------- K1: logits[b][s] = k[s][b][:] . Wp + bp ----------------
__global__ __launch_bounds__(256) void logits_kernel(
    const float* __restrict__ k, const float* __restrict__ Wp,
    const float* __restrict__ bp, float* __restrict__ logits)
{
  int wave = threadIdx.x >> 6, lane = threadIdx.x & 63;
  int idx = blockIdx.x * 4 + wave;           // 0..12799
  if (idx >= BSZ * SPAT) return;
  int b = idx / SPAT, s = idx - b * SPAT;
  const float4 kv = *(const float4*)(k + (s * BSZ + b) * DM + lane * 4);
  const float4 wv = *(const float4*)(Wp + lane * 4);
  float sum = kv.x * wv.x + kv.y * wv.y + kv.z * wv.z + kv.w * wv.w;
  #pragma unroll
  for (int off = 32; off; off >>= 1) sum += __shfl_xor(sum, off);
  if (lane == 0) logits[idx] = sum + bp[0];
}

// -------- K2: per-batch softmax -> entropy -> gaussian conv (same) --------
__global__ __launch_bounds__(256) void entropy_kernel(
    const float* __restrict__ logits, const float* __restrict__ gk,
    float* __restrict__ smooth)
{
  int b = blockIdx.x;
  int t = threadIdx.x;
  const float* L = logits + b * SPAT;
  __shared__ float entpad[SPAT + 28];
  __shared__ float red[256];

  for (int i = t; i < SPAT + 28; i += 256) entpad[i] = 0.f;

  float m = -INFINITY;
  for (int i = t; i < SPAT; i += 256) m = fmaxf(m, L[i]);
  red[t] = m; __syncthreads();
  for (int o = 128; o; o >>= 1) { if (t < o) red[t] = fmaxf(red[t], red[t + o]); __syncthreads(); }
  m = red[0]; __syncthreads();

  float lsum = 0.f;
  for (int i = t; i < SPAT; i += 256) {
    float e = expf(L[i] - m);
    entpad[14 + i] = e;
    lsum += e;
  }
  red[t] = lsum; __syncthreads();
  for (int o = 128; o; o >>= 1) { if (t < o) red[t] += red[t + o]; __syncthreads(); }
  float S = red[0]; __syncthreads();

  for (int i = t; i < SPAT; i += 256) {
    float p = entpad[14 + i] / S + 1e-8f;
    entpad[14 + i] = -p * logf(p) / 0.6931471805599453f;
  }
  __syncthreads();

  for (int i = t; i < SPAT; i += 256) {
    float acc = 0.f;
    #pragma unroll
    for (int u = 0; u < 29; ++u) acc += entpad[i + u] * gk[28 - u];
    smooth[b * SPAT + i] = acc;
  }
}

// -------- K3: sobel sign transitions -> cluster size -> meta --------
// meta: [0]=C, [1]=lo, [2]=rem, [3]=n_cl
__global__ __launch_bounds__(256) void clsize_kernel(
    const float* __restrict__ smooth, const float* __restrict__ sobel,
    int* __restrict__ meta)
{
  __shared__ int cnt;
  __shared__ float msum;
  int t = threadIdx.x;
  float sb0 = sobel[0], sb1 = sobel[1], sb2 = sobel[2];
  if (t == 0) msum = 0.f;
  for (int b = 0; b < BSZ; ++b) {
    const float* sm = smooth + b * SPAT;
    if (t == 0) cnt = 0;
    __syncthreads();
    int local = 0;
    for (int i = 1 + t; i < SPAT; i += 256) {
      float smL = (i - 2 >= 0) ? sm[i - 2] : 0.f;
      float a = sm[i - 1];
      float c = sm[i];
      float smR = (i + 1 < SPAT) ? sm[i + 1] : 0.f;
      float stepPrev = smL * sb2 + a * sb1 + c * sb0;   // step[i-1]
      float stepCur  = a * sb2 + c * sb1 + smR * sb0;   // step[i]
      int sPrev = stepPrev > 0.f;
      int sCur  = stepCur  > 0.f;
      local += (sPrev != sCur);
    }
    atomicAdd(&cnt, local);
    __syncthreads();
    if (t == 0) msum += 1600.f / (float)(cnt + 1);
    __syncthreads();
  }
  if (t == 0) {
    float mean = msum / 8.f;
    int C = (int)rintf(mean);
    if (C < 1) C = 1;
    int rem = SPAT % C;
    int lo = rem / 2;
    int n_cl = (SPAT - rem) / C;
    meta[0] = C; meta[1] = lo; meta[2] = rem; meta[3] = n_cl;
  }
}

// -------- K4: entropy-softmax weighted cluster pooling of k, v --------
__global__ __launch_bounds__(256) void cluster_kernel(
    const float* __restrict__ k, const float* __restrict__ v,
    const float* __restrict__ smooth, const int* __restrict__ meta,
    float* __restrict__ kc, float* __restrict__ vc)
{
  int c = blockIdx.x, b = blockIdx.y;
  int C = meta[0], lo = meta[1], n_cl = meta[3];
  if (c >= n_cl) return;
  __shared__ float w[SPAT];
  __shared__ float red[256];
  int t = threadIdx.x;
  const float* sm = smooth + b * SPAT + lo + c * C;

  float m = -INFINITY;
  for (int j = t; j < C; j += 256) m = fmaxf(m, sm[j]);
  red[t] = m; __syncthreads();
  for (int o = 128; o; o >>= 1) { if (t < o) red[t] = fmaxf(red[t], red[t + o]); __syncthreads(); }
  m = red[0]; __syncthreads();

  float lsum = 0.f;
  for (int j = t; j < C; j += 256) { float e = expf(sm[j] - m); w[j] = e; lsum += e; }
  red[t] = lsum; __syncthreads();
  for (int o = 128; o; o >>= 1) { if (t < o) red[t] += red[t + o]; __syncthreads(); }
  float S = red[0]; __syncthreads();
  for (int j = t; j < C; j += 256) w[j] = w[j] / S;
  __syncthreads();

  int d = t;
  int s0 = lo + c * C;
  const float* kp = k + (s0 * BSZ + b) * DM + d;
  const float* vp = v + (s0 * BSZ + b) * DM + d;
  float ak = 0.f, av = 0.f;
  for (int j = 0; j < C; ++j) {
    float wj = w[j];
    ak += wj * kp[0];
    av += wj * vp[0];
    kp += BSZ * DM; vp += BSZ * DM;
  }
  kc[(b * SPAT + c) * DM + d] = ak;
  vc[(b * SPAT + c) * DM + d] = av;
}

// -------- K5/K7: tiled fp32 GEMM: C[r][n] = A[r][:] @ W + bias --------
// mode 0: A gathered from q layout (s,b,d); out linear [b*1600+s]
// mode 1: A linear, rows with (r%1600)>=n_cl invalid (skipped)
// mode 2: A linear; out remapped to (s*8+b)*256 (final output transpose)
__global__ __launch_bounds__(256) void gemm_kernel(
    const float* __restrict__ A, const float* __restrict__ W,
    const float* __restrict__ bias, float* __restrict__ Cout,
    int mode, const int* __restrict__ meta)
{
  __shared__ float As[16][68];
  __shared__ float Ws[16][68];
  int bm = blockIdx.x, bn = blockIdx.y;
  int row0 = bm * 64, col0 = bn * 64;
  int n_cl = SPAT;
  if (mode == 1) {
    n_cl = meta[3];
    int s0 = row0 % SPAT;            // 1600/64==25 -> block stays within one b
    if (s0 >= n_cl) return;
  }
  int tid = threadIdx.x;
  int mA = tid >> 2, kA = (tid & 3) * 4;
  int kW = tid >> 4, nW = (tid & 15) * 4;
  int r = row0 + mA;
  const float* Arow;
  if (mode == 0) { int b = r / SPAT, s = r - b * SPAT; Arow = A + (s * BSZ + b) * DM; }
  else           { Arow = A + r * DM; }
  const float* Wrow = W + kW * DM + col0 + nW;
  int ty = tid >> 4, tx = tid & 15;
  float acc[4][4] = {};

  for (int k0 = 0; k0 < DM; k0 += 16) {
    float4 a4 = *(const float4*)(Arow + k0 + kA);
    As[kA + 0][mA] = a4.x; As[kA + 1][mA] = a4.y;
    As[kA + 2][mA] = a4.z; As[kA + 3][mA] = a4.w;
    float4 w4 = *(const float4*)(Wrow + k0 * DM);
    *(float4*)&Ws[kW][nW] = w4;
    __syncthreads();
    #pragma unroll
    for (int kk = 0; kk < 16; ++kk) {
      float4 av = *(const float4*)&As[kk][ty * 4];
      float4 wv = *(const float4*)&Ws[kk][tx * 4];
      acc[0][0] += av.x * wv.x; acc[0][1] += av.x * wv.y; acc[0][2] += av.x * wv.z; acc[0][3] += av.x * wv.w;
      acc[1][0] += av.y * wv.x; acc[1][1] += av.y * wv.y; acc[1][2] += av.y * wv.z; acc[1][3] += av.y * wv.w;
      acc[2][0] += av.z * wv.x; acc[2][1] += av.z * wv.y; acc[2][2] += av.z * wv.z; acc[2][3] += av.z * wv.w;
      acc[3][0] += av.w * wv.x; acc[3][1] += av.w * wv.y; acc[3][2] += av.w * wv.z; acc[3][3] += av.w * wv.w;
    }
    __syncthreads();
  }

  float4 bi = *(const float4*)(bias + col0 + tx * 4);
  #pragma unroll
  for (int i = 0; i < 4; ++i) {
    int rr = row0 + ty * 4 + i;
    int bb = rr / SPAT, ss = rr - bb * SPAT;
    if (mode == 1 && ss >= n_cl) continue;
    float* outp;
    if (mode == 2) outp = Cout + (ss * BSZ + bb) * DM + col0 + tx * 4;
    else           outp = Cout + rr * DM + col0 + tx * 4;
    float4 o;
    o.x = acc[i][0] + bi.x; o.y = acc[i][1] + bi.y;
    o.z = acc[i][2] + bi.z; o.w = acc[i][3] + bi.w;
    *(float4*)outp = o;
  }
}

// -------- K6: per-head attention over clusters (online softmax, /32) --------
#define CCHUNK 128
__global__ __launch_bounds__(256) void attn_kernel(
    const float* __restrict__ Qp, const float* __restrict__ Kp,
    const float* __restrict__ Vp, const int* __restrict__ meta,
    float* __restrict__ ctx)
{
  int sblk = blockIdx.x, b = blockIdx.y, h = blockIdx.z;
  int t = threadIdx.x;
  int s = sblk * 256 + t;
  int n_cl = meta[3];
  __shared__ float Ks[CCHUNK][DH];
  __shared__ float Vs[CCHUNK][DH];
  bool act = s < SPAT;

  float q[DH];
  if (act) {
    const float* qrow = Qp + (b * SPAT + s) * DM + h * DH;
    #pragma unroll
    for (int d = 0; d < DH; ++d) q[d] = qrow[d];
  }
  float m = -INFINITY, l = 0.f;
  float acc[DH];
  #pragma unroll
  for (int d = 0; d < DH; ++d) acc[d] = 0.f;

  for (int c0 = 0; c0 < n_cl; c0 += CCHUNK) {
    int cn = min(CCHUNK, n_cl - c0);
    for (int idx = t; idx < cn * DH; idx += 256) {
      int cj = idx >> 5, d = idx & 31;
      Ks[cj][d] = Kp[(b * SPAT + c0 + cj) * DM + h * DH + d];
      Vs[cj][d] = Vp[(b * SPAT + c0 + cj) * DM + h * DH + d];
    }
    __syncthreads();
    if (act) {
      for (int cj = 0; cj < cn; ++cj) {
        float sc = 0.f;
        #pragma unroll
        for (int d = 0; d < DH; ++d) sc += q[d] * Ks[cj][d];
        float nm = fmaxf(m, sc);
        float corr = expf(m - nm);
        float p = expf(sc - nm);
        l = l * corr + p;
        #pragma unroll
        for (int d = 0; d < DH; ++d) acc[d] = acc[d] * corr + p * Vs[cj][d];
        m = nm;
      }
    }
    __syncthreads();
  }

  if (act) {
    float inv = 1.f / (l * 32.f);
    float* orow = ctx + (b * SPAT + s) * DM + h * DH;
    #pragma unroll
    for (int d = 0; d < DH; ++d) orow[d] = acc[d] * inv;
  }
}

extern "C" void kernel_launch(void* const* d_in, const int* in_sizes, int n_in,
                              void* d_out, int out_size, void* d_ws, size_t ws_size,
                              hipStream_t stream) {
  const float* q  = (const float*)d_in[0];
  const float* k  = (const float*)d_in[1];
  const float* v  = (const float*)d_in[2];
  const float* Wq = (const float*)d_in[5];
  const float* bq = (const float*)d_in[6];
  const float* Wk = (const float*)d_in[7];
  const float* bk = (const float*)d_in[8];
  const float* Wv = (const float*)d_in[9];
  const float* bv = (const float*)d_in[10];
  const float* Wo = (const float*)d_in[11];
  const float* bo = (const float*)d_in[12];
  const float* Wp = (const float*)d_in[13];
  const float* bp = (const float*)d_in[14];
  const float* gk = (const float*)d_in[15];
  const float* sb = (const float*)d_in[16];
  float* out = (float*)d_out;

  char* ws = (char*)d_ws;
  int*   meta   = (int*)ws;                                  // 256 B
  float* logits = (float*)(ws + 256);                        // 12800 f32
  float* smooth = logits + BSZ * SPAT;                       // 12800 f32
  float* bufA   = (float*)(ws + 256 + 2 * BSZ * SPAT * 4);   // 13.1 MB: kc, then Vp
  float* bufB   = bufA + BSZ * SPAT * DM;                    // vc, then ctx
  float* bufC   = bufB + BSZ * SPAT * DM;                    // Qp
  float* bufD   = bufC + BSZ * SPAT * DM;                    // Kp

  logits_kernel<<<BSZ * SPAT / 4, 256, 0, stream>>>(k, Wp, bp, logits);
  entropy_kernel<<<BSZ, 256, 0, stream>>>(logits, gk, smooth);
  clsize_kernel<<<1, 256, 0, stream>>>(smooth, sb, meta);
  cluster_kernel<<<dim3(SPAT, BSZ), 256, 0, stream>>>(k, v, smooth, meta, bufA, bufB);
  gemm_kernel<<<dim3(200, 4), 256, 0, stream>>>(q,    Wq, bq, bufC, 0, meta);  // Qp
  gemm_kernel<<<dim3(200, 4), 256, 0, stream>>>(bufA, Wk, bk, bufD, 1, meta);  // Kp
  gemm_kernel<<<dim3(200, 4), 256, 0, stream>>>(bufB, Wv, bv, bufA, 1, meta);  // Vp (reuse kc)
  attn_kernel<<<dim3((SPAT + 255) / 256, BSZ, NH), 256, 0, stream>>>(bufC, bufD, bufA, meta, bufB); // ctx (reuse vc)
  gemm_kernel<<<dim3(200, 4), 256, 0, stream>>>(bufB, Wo, bo, out, 2, meta);   // final + transpose
}